// Round 1
// baseline (2298.650 us; speedup 1.0000x reference)
//
#include <hip/hip_runtime.h>
#include <hip/hip_bf16.h>
#include <math.h>

#define N_NODES 10000
#define N_EDGES 160000
#define EB 16

__device__ __forceinline__ float sigmoidf_(float x){ return 1.f/(1.f+__expf(-x)); }

// ---------------- Kernel A: node transforms ----------------
// s_src/s_dst = s @ w/sqrt(128)+b ; v_src/v_dst = einsum(v,w)/8
__global__ __launch_bounds__(256) void k_node(
    const float* __restrict__ node_input,
    const float* __restrict__ w_src0, const float* __restrict__ b_src0,
    const float* __restrict__ w_src1,
    const float* __restrict__ w_dst0, const float* __restrict__ b_dst0,
    const float* __restrict__ w_dst1,
    float* __restrict__ ns_src, float* __restrict__ ns_dst,
    float* __restrict__ nv_src, float* __restrict__ nv_dst)
{
  __shared__ float sNI[8*321];
  int t = threadIdx.x;
  int n0 = blockIdx.x*8;
  for (int idx=t; idx<8*320; idx+=256){
    int nd = idx/320, r = idx - nd*320;
    sNI[nd*321+r] = node_input[(size_t)(n0+nd)*320 + r];
  }
  __syncthreads();
  {
    int o = t & 127, half = t >> 7;
    const float* w = half ? w_dst0 : w_src0;
    const float* b = half ? b_dst0 : b_src0;
    float* outp = half ? ns_dst : ns_src;
    float acc[8];
    #pragma unroll
    for (int nd=0;nd<8;nd++) acc[nd]=0.f;
    for (int k=0;k<128;k++){
      float wv = w[k*128+o];
      #pragma unroll
      for (int nd=0;nd<8;nd++) acc[nd] += sNI[nd*321+k]*wv;
    }
    const float rs = 0.08838834764831845f; // 1/sqrt(128)
    float bo = b[o];
    #pragma unroll
    for (int nd=0;nd<8;nd++) outp[(size_t)(n0+nd)*128+o] = acc[nd]*rs + bo;
  }
  if (t < 192){
    int o = t & 63, c = t >> 6;
    for (int half=0; half<2; half++){
      const float* w = half ? w_dst1 : w_src1;
      float* outp = half ? nv_dst : nv_src;
      float acc[8];
      #pragma unroll
      for (int nd=0;nd<8;nd++) acc[nd]=0.f;
      for (int i=0;i<64;i++){
        float wv = w[i*64+o];
        #pragma unroll
        for (int nd=0;nd<8;nd++) acc[nd] += sNI[nd*321+128+i*3+c]*wv;
      }
      #pragma unroll
      for (int nd=0;nd<8;nd++) outp[(size_t)(n0+nd)*192 + o*3 + c] = acc[nd]*0.125f;
    }
  }
}

// ---------------- Kernel C: fused edge pipeline ----------------
// MLP(64->64->64->448) -> w chunks -> d0/d1 -> m0 (f32, alpha logits) / m1,val_s (bf16 out)
__global__ __launch_bounds__(512) void k_edge(
  const float* __restrict__ edge_attr, const float* __restrict__ edge_scalars,
  const int* __restrict__ edge_src, const int* __restrict__ edge_dst,
  const float* __restrict__ ns_src, const float* __restrict__ ns_dst,
  const float* __restrict__ nv_src, const float* __restrict__ nv_dst,
  const float* __restrict__ rw1, const float* __restrict__ rb1,
  const float* __restrict__ rw2, const float* __restrict__ rb2,
  const float* __restrict__ rw3, const float* __restrict__ rb3,
  const float* __restrict__ lw0, const float* __restrict__ lb0,
  const float* __restrict__ lw1, const float* __restrict__ alpha_dot,
  float* __restrict__ galpha, __hip_bfloat16* __restrict__ gval,
  __hip_bfloat16* __restrict__ gm1)
{
  // LDS layout (floats), total 14592 (58.4 KB), with region overlays:
  __shared__ float L[14592];
  float* sMV  = L;            // 16*193 = 3088   (persistent)
  float* sEA  = L + 3088;     // 16*8   = 128    (persistent: es, ev0..2)
  float* sASV = L + 3216;     // 16*129 = 2064   (persistent: w_sv*ms)
  float* sBVS = L + 5280;     // 16*65  = 1040   (persistent: w_vs*es)
  float* sWV1 = L + 6320;     // 16*65  = 1040   (persistent: w_vv1/sqrt2)
  float* RX   = L + 7360;     // region X: 3088
  float* sES  = RX;           // 16*65 (P0-P1)
  float* sD0  = RX;           // 16*193 (P3-P4)
  float* sD1  = RX;           // 16*129 (P5)
  float* RY   = L + 10448;    // region Y: 4144
  float* sH1  = RY;           // 16*65 (P1-P2)
  float* sH2  = RY + 1040;    // 16*65 (P2-P3)
  float* sMS  = RY + 2080;    // 16*129 (P0-P3)
  float* sM0  = RY;           // 16*161 = 2576 (P4, overlays H1/H2/MS-head)

  int t = threadIdx.x;
  int e0 = blockIdx.x * EB;

  // ---- P0: loads & gathers ----
  if (t < 64){ int e=t>>2, c=t&3; sEA[e*8+c] = edge_attr[(size_t)(e0+e)*4+c]; }
  for (int idx=t; idx<EB*64; idx+=512){
    int e=idx>>6, i=idx&63;
    sES[e*65+i] = edge_scalars[(size_t)(e0+e)*64+i];
  }
  {
    int e = t>>5, l = t&31;
    int s = edge_src[e0+e], d = edge_dst[e0+e];
    #pragma unroll
    for (int k=0;k<4;k++){ int i=l+32*k; sMS[e*129+i] = ns_src[(size_t)s*128+i] + ns_dst[(size_t)d*128+i]; }
    #pragma unroll
    for (int k=0;k<6;k++){ int i=l+32*k; sMV[e*193+i] = nv_src[(size_t)s*192+i] + nv_dst[(size_t)d*192+i]; }
  }
  __syncthreads();

  // ---- P1: h1 = silu(es @ rw1 + rb1) ----
  {
    int e = t>>5, og = t&31;
    float a0 = rb1[og], a1 = rb1[og+32];
    for (int i=0;i<64;i++){
      float x = sES[e*65+i];
      a0 += x * rw1[i*64+og];
      a1 += x * rw1[i*64+og+32];
    }
    sH1[e*65+og]    = a0*sigmoidf_(a0);
    sH1[e*65+og+32] = a1*sigmoidf_(a1);
  }
  __syncthreads();

  // ---- P2: h2 = silu(h1 @ rw2 + rb2) ----
  {
    int e = t>>5, og = t&31;
    float a0 = rb2[og], a1 = rb2[og+32];
    for (int i=0;i<64;i++){
      float x = sH1[e*65+i];
      a0 += x * rw2[i*64+og];
      a1 += x * rw2[i*64+og+32];
    }
    sH2[e*65+og]    = a0*sigmoidf_(a0);
    sH2[e*65+og+32] = a1*sigmoidf_(a1);
  }
  __syncthreads();

  // ---- P3: w = h2 @ rw3 + rb3, chunked & consumed immediately ----
  {
    int ty = t>>6, tx = t&63;
    int eA = ty*2, eB = eA+1;
    float esA = sEA[eA*8+0], esB = sEA[eB*8+0];
    for (int j=0;j<7;j++){
      int o = tx + 64*j;
      float b3 = rb3[o];
      float a0 = b3, a1 = b3;
      for (int i=0;i<64;i++){
        float r = rw3[i*448+o];
        a0 += sH2[eA*65+i]*r;
        a1 += sH2[eB*65+i]*r;
      }
      if (j < 2){                       // w_ss -> d0[0:128] = w_ss*ms*es
        sD0[eA*193+o] = a0 * sMS[eA*129+o] * esA;
        sD0[eB*193+o] = a1 * sMS[eB*129+o] * esB;
      } else if (j < 4){ int oo=o-128;  // w_sv -> a_sv = w_sv*ms
        sASV[eA*129+oo] = a0 * sMS[eA*129+oo];
        sASV[eB*129+oo] = a1 * sMS[eB*129+oo];
      } else if (j == 4){ int oo=o-256; // w_vs -> b_vs = w_vs*es
        sBVS[eA*65+oo] = a0 * esA;
        sBVS[eB*65+oo] = a1 * esB;
      } else if (j == 5){ int oo=o-320; // w_vv0 -> d0[128+oo] = w_vv0*(mv.ev)/sqrt3
        const float rs3 = 0.5773502691896258f;
        float dA = sMV[eA*193+oo*3+0]*sEA[eA*8+1] + sMV[eA*193+oo*3+1]*sEA[eA*8+2] + sMV[eA*193+oo*3+2]*sEA[eA*8+3];
        float dB = sMV[eB*193+oo*3+0]*sEA[eB*8+1] + sMV[eB*193+oo*3+1]*sEA[eB*8+2] + sMV[eB*193+oo*3+2]*sEA[eB*8+3];
        sD0[eA*193+128+oo] = a0 * dA * rs3;
        sD0[eB*193+128+oo] = a1 * dB * rs3;
      } else { int oo=o-384;            // w_vv1 (fold 1/sqrt2)
        const float rs2 = 0.7071067811865476f;
        sWV1[eA*65+oo] = a0 * rs2;
        sWV1[eB*65+oo] = a1 * rs2;
      }
    }
  }
  __syncthreads();

  // ---- P4: m0 = d0 @ lw0 / sqrt(192) + lb0 ----
  {
    int ty = t>>6, tx = t&63;
    const float rs192 = 0.07216878364870323f;
    for (int e2=0;e2<2;e2++){
      int e = ty*2+e2;
      for (int j=0;j<3;j++){
        int o = tx + 64*j;
        if (o < 160){
          float acc = 0.f;
          for (int i=0;i<192;i++) acc += sD0[e*193+i]*lw0[i*160+o];
          sM0[e*161+o] = acc*rs192 + lb0[o];
        }
      }
    }
  }
  __syncthreads();

  // alpha logits (f32)
  if (t < 64){
    int e=t>>2, h=t&3;
    float logit = 0.f;
    #pragma unroll
    for (int k=0;k<8;k++){
      float a = sM0[e*161 + h*40 + k];
      float act = 0.6f*a + 0.4f*a*(2.f*sigmoidf_(a)-1.f);
      logit += act * alpha_dot[h*8+k];
    }
    galpha[(size_t)(e0+e)*4+h] = logit;
  }
  // val_s (bf16)
  for (int idx=t; idx<EB*128; idx+=512){
    int e=idx>>7, q=idx&127, h=q>>5, k=q&31;
    gval[(size_t)(e0+e)*128+q] = __float2bfloat16(sM0[e*161 + h*40 + 8 + k]);
  }

  // ---- P5a: A[e][o] = sum_i asv[e][i]*lw1[i][o] (o1a part, c-independent) ----
  float regA[2];
  {
    int ty = t>>6, tx = t&63;
    for (int e2=0;e2<2;e2++){
      int e = ty*2+e2;
      float acc = 0.f;
      for (int i=0;i<128;i++) acc += sASV[e*129+i]*lw1[i*64+tx];
      regA[e2]=acc;
    }
  }

  // ---- P5b: per-c build d1 rows 128..255 and finish m1 ----
  const float r16 = 0.0625f;
  for (int c=0;c<3;c++){
    if (c) __syncthreads();            // protect sD1 rewrite
    int ca = (c+1)%3, cb = (c+2)%3;
    for (int idx=t; idx<EB*128; idx+=512){
      int e=idx>>7, ii=idx&127;
      float v;
      if (ii < 64){
        v = sBVS[e*65+ii] * sMV[e*193+ii*3+c];
      } else {
        int iii = ii-64;
        float a1 = sMV[e*193+iii*3+ca], a2 = sMV[e*193+iii*3+cb];
        float b1 = sEA[e*8+1+ca],        b2 = sEA[e*8+1+cb];
        v = sWV1[e*65+iii] * (a1*b2 - a2*b1);
      }
      sD1[e*129+ii] = v;
    }
    __syncthreads();
    {
      int ty = t>>6, tx = t&63;
      for (int e2=0;e2<2;e2++){
        int e = ty*2+e2;
        float acc = regA[e2]*sEA[e*8+1+c];
        for (int i=0;i<128;i++) acc += sD1[e*129+i]*lw1[(128+i)*64+tx];
        gm1[(size_t)((size_t)(e0+e)*3+c)*64+tx] = __float2bfloat16(acc*r16);
      }
    }
  }
}

// ---------------- Kernel D: per-dst softmax + aggregation + output transform ----------------
__global__ __launch_bounds__(320) void k_agg(
  const int* __restrict__ edge_dst,
  const float* __restrict__ galpha, const __hip_bfloat16* __restrict__ gval,
  const __hip_bfloat16* __restrict__ gm1,
  const float* __restrict__ pw0, const float* __restrict__ pb0,
  const float* __restrict__ pw1,
  float* __restrict__ out)
{
  __shared__ float sRed[256], sW[256], sAm[4], sInv[4], sNS[128], sNV[192];
  int t = threadIdx.x;
  int n = blockIdx.x;
  // segment bounds via binary search (edge_dst sorted)
  int lo, hi;
  {
    int a=0,b=N_EDGES;
    while(a<b){int m=(a+b)>>1; if (edge_dst[m] < n) a=m+1; else b=m;}
    lo=a; a=lo; b=N_EDGES;
    while(a<b){int m=(a+b)>>1; if (edge_dst[m] < n+1) a=m+1; else b=m;}
    hi=a;
  }
  // per-head max
  if (t < 256){
    int g=t>>2, h=t&3;
    float m=-1e30f;
    for (int e=lo+g; e<hi; e+=64) m = fmaxf(m, galpha[(size_t)e*4+h]);
    sRed[t]=m;
  }
  __syncthreads();
  for (int s=32; s>=1; s>>=1){
    if (t < s*4) sRed[t] = fmaxf(sRed[t], sRed[t+s*4]);
    __syncthreads();
  }
  if (t<4) sAm[t] = (hi>lo) ? sRed[t] : 0.f;
  __syncthreads();
  // denom
  if (t < 256){
    int g=t>>2, h=t&3; float ssum=0.f;
    for (int e=lo+g; e<hi; e+=64) ssum += __expf(galpha[(size_t)e*4+h]-sAm[h]);
    sRed[t]=ssum;
  }
  __syncthreads();
  for (int s=32; s>=1; s>>=1){
    if (t < s*4) sRed[t] += sRed[t+s*4];
    __syncthreads();
  }
  if (t<4) sInv[t] = 1.f / fmaxf(sRed[t], 1e-12f);
  __syncthreads();
  // weighted accumulation
  float acc = 0.f;
  int cq=0, oq=0, hq=0;
  if (t < 128){ hq = t>>5; }
  else { int q=t-128; cq=q>>6; oq=q&63; hq=oq>>4; }
  for (int base=lo; base<hi; base+=64){
    int nn = min(64, hi-base);
    if (t < 256){ int j=t>>2,h=t&3; if (j<nn) sW[t] = __expf(galpha[(size_t)(base+j)*4+h]-sAm[h])*sInv[h]; }
    __syncthreads();
    if (t < 128){
      for (int j=0;j<nn;j++) acc += sW[j*4+hq]*__bfloat162float(gval[(size_t)(base+j)*128+t]);
    } else {
      for (int j=0;j<nn;j++) acc += sW[j*4+hq]*__bfloat162float(gm1[(size_t)((size_t)(base+j)*3+cq)*64+oq]);
    }
    __syncthreads();
  }
  if (t < 128) sNS[t]=acc; else sNV[oq*3+cq]=acc;
  __syncthreads();
  // output transforms
  if (t < 128){
    float a = 0.f;
    for (int k=0;k<128;k++) a += sNS[k]*pw0[k*128+t];
    out[(size_t)n*320+t] = a*0.08838834764831845f + pb0[t];
  } else {
    float a = 0.f;
    for (int i=0;i<64;i++) a += sNV[i*3+cq]*pw1[i*64+oq];
    out[(size_t)n*320+128+oq*3+cq] = a*0.125f;
  }
}

extern "C" void kernel_launch(void* const* d_in, const int* in_sizes, int n_in,
                              void* d_out, int out_size, void* d_ws, size_t ws_size,
                              hipStream_t stream)
{
  const float* node_input  = (const float*)d_in[0];
  const float* edge_attr   = (const float*)d_in[1];
  const float* edge_scalars= (const float*)d_in[2];
  const int*   edge_src    = (const int*)d_in[3];
  const int*   edge_dst    = (const int*)d_in[4];
  const float* w_src0=(const float*)d_in[5];  const float* b_src0=(const float*)d_in[6];
  const float* w_src1=(const float*)d_in[7];
  const float* w_dst0=(const float*)d_in[8];  const float* b_dst0=(const float*)d_in[9];
  const float* w_dst1=(const float*)d_in[10];
  const float* rw1=(const float*)d_in[11];    const float* rb1=(const float*)d_in[12];
  const float* rw2=(const float*)d_in[13];    const float* rb2=(const float*)d_in[14];
  const float* rw3=(const float*)d_in[15];    const float* rb3=(const float*)d_in[16];
  const float* lw0=(const float*)d_in[17];    const float* lb0=(const float*)d_in[18];
  const float* lw1=(const float*)d_in[19];
  const float* alpha_dot=(const float*)d_in[20];
  const float* pw0=(const float*)d_in[21];    const float* pb0=(const float*)d_in[22];
  const float* pw1=(const float*)d_in[23];
  float* out = (float*)d_out;

  // workspace layout
  float* ns_src = (float*)d_ws;                       // N*128
  float* ns_dst = ns_src + (size_t)N_NODES*128;       // N*128
  float* nv_src = ns_dst + (size_t)N_NODES*128;       // N*192
  float* nv_dst = nv_src + (size_t)N_NODES*192;       // N*192
  float* galpha = nv_dst + (size_t)N_NODES*192;       // E*4 (f32)
  __hip_bfloat16* gval = (__hip_bfloat16*)(galpha + (size_t)N_EDGES*4); // E*128 bf16
  __hip_bfloat16* gm1  = gval + (size_t)N_EDGES*128;                    // E*192 bf16

  k_node<<<N_NODES/8, 256, 0, stream>>>(node_input, w_src0,b_src0,w_src1,
                                        w_dst0,b_dst0,w_dst1,
                                        ns_src,ns_dst,nv_src,nv_dst);
  k_edge<<<N_EDGES/EB, 512, 0, stream>>>(edge_attr, edge_scalars, edge_src, edge_dst,
                                         ns_src,ns_dst,nv_src,nv_dst,
                                         rw1,rb1,rw2,rb2,rw3,rb3,
                                         lw0,lb0,lw1,alpha_dot,
                                         galpha,gval,gm1);
  k_agg<<<N_NODES, 320, 0, stream>>>(edge_dst, galpha, gval, gm1, pw0,pb0,pw1, out);
}